// Round 1
// baseline (224.777 us; speedup 1.0000x reference)
//
#include <hip/hip_runtime.h>
#include <math.h>

#define DEV __device__ __forceinline__

namespace {

struct C2 { float x, y; };

// ---------------- workspace layout (float offsets) ----------------
constexpr size_t OFF_CS   = 0;        // 1024 tokens * 80 gates * 2 (cos,sin)  = 163840
constexpr size_t OFF_QFF  = 163840;   // 40 gates * 2                           = 80
constexpr size_t OFF_LCU  = 163920;   // 32 * float2                            = 64
constexpr size_t OFF_DEN  = 163984;   // 1
constexpr size_t OFF_NRM  = 163988;   // 32
constexpr size_t OFF_MONO = 164096;   // 32*1024*float2                         = 65536
constexpr size_t OFF_ACC  = 229632;   // 65536
constexpr size_t OFF_ST   = 295168;   // 1024*1024*float2                       = 2097152
constexpr size_t OFF_EV   = 2392320;  // 32*30                                  = 960
constexpr size_t OFF_H    = 2393280;  // 32*512                                 = 16384
// total ~2.41M floats ~ 9.6 MB

// ---------------- gate primitives ----------------
// amplitude index i = (reg<<6) | lane ; bit p of i: p<6 -> lane bit, p>=6 -> reg bit
// wire w lives at bit position P = 9 - w.

template<int P>
DEV void ry_gate(C2 v[16], int lane, float c, float s) {
  if constexpr (P >= 6) {
    constexpr int rm = 1 << (P - 6);
#pragma unroll
    for (int r = 0; r < 16; ++r) {
      if ((r & rm) == 0) {
        C2 a = v[r], b = v[r | rm];
        v[r].x      = fmaf(c, a.x, -s * b.x);
        v[r].y      = fmaf(c, a.y, -s * b.y);
        v[r | rm].x = fmaf(s, a.x,  c * b.x);
        v[r | rm].y = fmaf(s, a.y,  c * b.y);
      }
    }
  } else {
    constexpr int lm = 1 << P;
    float sg = (lane & lm) ? s : -s;   // v' = c*v + sg*partner
#pragma unroll
    for (int r = 0; r < 16; ++r) {
      float px = __shfl_xor(v[r].x, lm, 64);
      float py = __shfl_xor(v[r].y, lm, 64);
      v[r].x = fmaf(c, v[r].x, sg * px);
      v[r].y = fmaf(c, v[r].y, sg * py);
    }
  }
}

// CRX: apply RX(theta) on target where ctrl bit == 1.
// RX is role-symmetric on the pair: v'.x = c*vx + s*py ; v'.y = c*vy - s*px
template<int PC, int PT>
DEV void crx_gate(C2 v[16], int lane, float c, float s) {
  if constexpr (PT >= 6) {
    constexpr int tm = 1 << (PT - 6);
#pragma unroll
    for (int r = 0; r < 16; ++r) {
      if ((r & tm) == 0) {
        if constexpr (PC >= 6) {
          constexpr int cm = 1 << (PC - 6);
          if ((r & cm) != 0) {
            C2 a = v[r], b = v[r | tm];
            v[r].x      = fmaf(c, a.x,  s * b.y);
            v[r].y      = fmaf(c, a.y, -s * b.x);
            v[r | tm].x = fmaf(c, b.x,  s * a.y);
            v[r | tm].y = fmaf(c, b.y, -s * a.x);
          }
        } else {
          constexpr int cl = 1 << PC;
          bool ct = (lane & cl) != 0;
          C2 a = v[r], b = v[r | tm];
          float nax = fmaf(c, a.x,  s * b.y);
          float nay = fmaf(c, a.y, -s * b.x);
          float nbx = fmaf(c, b.x,  s * a.y);
          float nby = fmaf(c, b.y, -s * a.x);
          v[r].x      = ct ? nax : a.x;
          v[r].y      = ct ? nay : a.y;
          v[r | tm].x = ct ? nbx : b.x;
          v[r | tm].y = ct ? nby : b.y;
        }
      }
    }
  } else {
    constexpr int tm = 1 << PT;
#pragma unroll
    for (int r = 0; r < 16; ++r) {
      if constexpr (PC >= 6) {
        constexpr int cm = 1 << (PC - 6);
        if ((r & cm) == 0) continue;   // uniform across lanes: no divergence
      }
      float px = __shfl_xor(v[r].x, tm, 64);
      float py = __shfl_xor(v[r].y, tm, 64);
      float nx = fmaf(c, v[r].x,  s * py);
      float ny = fmaf(c, v[r].y, -s * px);
      if constexpr (PC >= 6) {
        v[r].x = nx; v[r].y = ny;
      } else {
        constexpr int cl = 1 << PC;
        bool ct = (lane & cl) != 0;
        v[r].x = ct ? nx : v[r].x;
        v[r].y = ct ? ny : v[r].y;
      }
    }
  }
}

#define RYG(w, g)       ry_gate<9-(w)>(v, lane, cs[2*(g)], cs[2*(g)+1])
#define CRXG(cw, tw, g) crx_gate<9-(cw), 9-(tw)>(v, lane, cs[2*(g)], cs[2*(g)+1])

// One ansatz-14 layer = 40 gates, params cs[0..79] as (cos,sin) pairs
DEV void apply_layer(C2 v[16], int lane, const float* __restrict__ cs) {
  RYG(0,0); RYG(1,1); RYG(2,2); RYG(3,3); RYG(4,4);
  RYG(5,5); RYG(6,6); RYG(7,7); RYG(8,8); RYG(9,9);
  CRXG(9,0,10); CRXG(8,9,11); CRXG(7,8,12); CRXG(6,7,13); CRXG(5,6,14);
  CRXG(4,5,15); CRXG(3,4,16); CRXG(2,3,17); CRXG(1,2,18); CRXG(0,1,19);
  RYG(0,20); RYG(1,21); RYG(2,22); RYG(3,23); RYG(4,24);
  RYG(5,25); RYG(6,26); RYG(7,27); RYG(8,28); RYG(9,29);
  CRXG(9,8,30); CRXG(0,9,31); CRXG(1,0,32); CRXG(2,1,33); CRXG(3,2,34);
  CRXG(4,3,35); CRXG(5,4,36); CRXG(6,5,37); CRXG(7,6,38); CRXG(8,7,39);
}

template<int P>
DEV void measure_wire(const C2 v[16], int lane, float* ev, int w) {
  float x = 0.f, y = 0.f, z = 0.f;
  if constexpr (P >= 6) {
    constexpr int rm = 1 << (P - 6);
#pragma unroll
    for (int r = 0; r < 16; ++r) {
      if ((r & rm) == 0) {
        C2 a = v[r], b = v[r | rm];
        x += a.x*b.x + a.y*b.y;
        y += a.x*b.y - a.y*b.x;
        z += (a.x*a.x + a.y*a.y) - (b.x*b.x + b.y*b.y);
      }
    }
  } else {
    constexpr int lm = 1 << P;
#pragma unroll
    for (int r = 0; r < 16; ++r) {
      float px = __shfl_xor(v[r].x, lm, 64);
      float py = __shfl_xor(v[r].y, lm, 64);
      if ((lane & lm) == 0) {
        C2 a = v[r];
        x += a.x*px + a.y*py;
        y += a.x*py - a.y*px;
        z += (a.x*a.x + a.y*a.y) - (px*px + py*py);
      }
    }
  }
  for (int s = 1; s < 64; s <<= 1) {
    x += __shfl_xor(x, s, 64);
    y += __shfl_xor(y, s, 64);
    z += __shfl_xor(z, s, 64);
  }
  if (lane == 0) {
    ev[w]      = 2.f * x;
    ev[10 + w] = 2.f * y;
    ev[20 + w] = z;
  }
}

DEV void measure_all(const C2 v[16], int lane, float* ev) {
  measure_wire<9>(v, lane, ev, 0);
  measure_wire<8>(v, lane, ev, 1);
  measure_wire<7>(v, lane, ev, 2);
  measure_wire<6>(v, lane, ev, 3);
  measure_wire<5>(v, lane, ev, 4);
  measure_wire<4>(v, lane, ev, 5);
  measure_wire<3>(v, lane, ev, 6);
  measure_wire<2>(v, lane, ev, 7);
  measure_wire<1>(v, lane, ev, 8);
  measure_wire<0>(v, lane, ev, 9);
}

// ---------------- kernels ----------------

// K0: normalize lcu, |coeffs| sum, qff cos/sin. 1 block x 64.
__global__ __launch_bounds__(64) void k_prep(const float* __restrict__ lr,
                                             const float* __restrict__ li,
                                             const float* __restrict__ coef,
                                             const float* __restrict__ qff,
                                             float* __restrict__ ws) {
  int lane = threadIdx.x;
  float re = 0.f, im = 0.f;
  if (lane < 32) { re = lr[lane]; im = li[lane]; }
  float tot = sqrtf(re * re + im * im);
  for (int s = 1; s < 64; s <<= 1) tot += __shfl_xor(tot, s, 64);
  float L = fmaxf(tot, 1e-12f);
  if (lane < 32) {
    ws[OFF_LCU + 2 * lane]     = re / L;
    ws[OFF_LCU + 2 * lane + 1] = im / L;
  }
  float dv = (lane < 4) ? fabsf(coef[lane]) : 0.f;
  for (int s = 1; s < 64; s <<= 1) dv += __shfl_xor(dv, s, 64);
  if (lane == 0) ws[OFF_DEN] = dv;
  if (lane < 40) {
    float th = 0.5f * qff[lane];
    ws[OFF_QFF + 2 * lane]     = cosf(th);
    ws[OFF_QFF + 2 * lane + 1] = sinf(th);
  }
}

// K_init: mono = e0, acc = coeffs[0]*e0. 128x256.
__global__ void k_init(float* __restrict__ ws, const float* __restrict__ coef) {
  int idx = blockIdx.x * 256 + threadIdx.x;   // 0..32767 over (b,i)
  float c0 = coef[0];
  bool z = (idx & 1023) == 0;
  float2* mono = (float2*)(ws + OFF_MONO);
  float2* acc  = (float2*)(ws + OFF_ACC);
  mono[idx] = make_float2(z ? 1.f : 0.f, 0.f);
  acc[idx]  = make_float2(z ? c0 : 0.f, 0.f);
}

// K1: angles = emb[x] @ w_ang.T + b_ang -> (cos,sin)(theta/2). one token/block.
__global__ __launch_bounds__(128) void k_angles(const int* __restrict__ x,
                                                const float* __restrict__ emb,
                                                const float* __restrict__ w_ang,
                                                const float* __restrict__ b_ang,
                                                float* __restrict__ ws) {
  __shared__ float4 e4[128];   // 512 floats
  int tok = blockIdx.x;
  int tid = threadIdx.x;
  int row = x[tok];
  e4[tid] = ((const float4*)(emb + (size_t)row * 512))[tid];
  __syncthreads();
  if (tid < 80) {
    const float4* wr = (const float4*)(w_ang + (size_t)tid * 512);
    float acc = b_ang[tid];
#pragma unroll 4
    for (int j = 0; j < 128; ++j) {
      float4 w = wr[j];
      float4 e = e4[j];
      acc = fmaf(w.x, e.x, acc);
      acc = fmaf(w.y, e.y, acc);
      acc = fmaf(w.z, e.z, acc);
      acc = fmaf(w.w, e.w, acc);
    }
    float th = 0.5f * acc;
    ws[OFF_CS + (size_t)tok * 160 + 2 * tid]     = cosf(th);
    ws[OFF_CS + (size_t)tok * 160 + 2 * tid + 1] = sinf(th);
  }
}

// K2: evolve. one wave per (b,t) state; full state in 32 VGPR/lane.
__global__ __launch_bounds__(256) void k_evolve(float* __restrict__ ws) {
  __shared__ float cs_lds[640];
  int tid = threadIdx.x;
  const float* csg = ws + OFF_CS + (size_t)blockIdx.x * 640;
  for (int i = tid; i < 640; i += 256) cs_lds[i] = csg[i];
  __syncthreads();
  int wid = tid >> 6, lane = tid & 63;
  int state = blockIdx.x * 4 + wid;
  int b = state >> 5, t = state & 31;
  const float2* mono = (const float2*)(ws + OFF_MONO) + (size_t)b * 1024;
  C2 v[16];
#pragma unroll
  for (int r = 0; r < 16; ++r) {
    float2 m = mono[(r << 6) | lane];
    v[r].x = m.x; v[r].y = m.y;
  }
  const float* csw = &cs_lds[wid * 160];
#pragma unroll 1
  for (int l = 0; l < 2; ++l)
    apply_layer(v, lane, csw + l * 80);
  float2 w = ((const float2*)(ws + OFF_LCU))[t];
  float2* st = (float2*)(ws + OFF_ST) + (size_t)state * 1024;
#pragma unroll
  for (int r = 0; r < 16; ++r) {
    st[(r << 6) | lane] = make_float2(w.x * v[r].x - w.y * v[r].y,
                                      w.x * v[r].y + w.y * v[r].x);
  }
}

// K3: mono[b] = sum_t st[b,t] (lcu-scaled already); acc += coeffs[k]*mono. 128x256.
__global__ void k_reduce(float* __restrict__ ws, const float* __restrict__ coef, int k) {
  int idx = blockIdx.x * 256 + threadIdx.x;   // 0..32767 over (b,i)
  int b = idx >> 10, i = idx & 1023;
  const float2* st = (const float2*)(ws + OFF_ST) + (size_t)b * 32768 + i;
  float sx = 0.f, sy = 0.f;
#pragma unroll
  for (int t = 0; t < 32; ++t) {
    float2 vv = st[t * 1024];
    sx += vv.x; sy += vv.y;
  }
  float2* mono = (float2*)(ws + OFF_MONO);
  float2* acc  = (float2*)(ws + OFF_ACC);
  mono[idx] = make_float2(sx, sy);
  float ck = coef[k];
  float2 a = acc[idx];
  a.x = fmaf(ck, sx, a.x);
  a.y = fmaf(ck, sy, a.y);
  acc[idx] = a;
}

// K5: qsvt_state = acc/den; norm; normalize; 1-layer qff circuit; measure XYZ. 1 wave/b.
__global__ __launch_bounds__(64) void k_final(float* __restrict__ ws) {
  int lane = threadIdx.x;
  int b = blockIdx.x;
  const float2* acc = (const float2*)(ws + OFF_ACC) + (size_t)b * 1024;
  float invd = 1.f / ws[OFF_DEN];
  C2 v[16];
  float ssum = 0.f;
#pragma unroll
  for (int r = 0; r < 16; ++r) {
    float2 m = acc[(r << 6) | lane];
    v[r].x = m.x * invd; v[r].y = m.y * invd;
    ssum += v[r].x * v[r].x + v[r].y * v[r].y;
  }
  for (int s = 1; s < 64; s <<= 1) ssum += __shfl_xor(ssum, s, 64);
  float nrm = sqrtf(ssum);
  if (lane == 0) ws[OFF_NRM + b] = nrm;
  float sc = 1.f / fmaxf(nrm, 1e-12f);
#pragma unroll
  for (int r = 0; r < 16; ++r) { v[r].x *= sc; v[r].y *= sc; }
  apply_layer(v, lane, ws + OFF_QFF);
  measure_all(v, lane, ws + OFF_EV + b * 30);
}

// K6: h = relu(ev @ w1.T + b1); also mean(norm) -> out[1024000]. 64x256.
__global__ void k_mlp1(float* __restrict__ ws, const float* __restrict__ w1,
                       const float* __restrict__ b1, float* __restrict__ out) {
  int idx = blockIdx.x * 256 + threadIdx.x;   // 0..16383 over (b,j)
  int b = idx >> 9, j = idx & 511;
  const float* ev = ws + OFF_EV + b * 30;
  const float* wr = w1 + (size_t)j * 30;
  float a = b1[j];
#pragma unroll
  for (int q = 0; q < 30; ++q) a = fmaf(ev[q], wr[q], a);
  ws[OFF_H + idx] = fmaxf(a, 0.f);
  if (idx == 0) {
    float s = 0.f;
    for (int i = 0; i < 32; ++i) s += ws[OFF_NRM + i];
    out[32000u * 32u] = s * (1.f / 32.f);
  }
}

// K7: logits = h @ w2.T + b2.  M=32, N=32000, K=512.
// block: 256 thr, 64 vocab rows. wave: 4 rows/iter; lane = (row_sub[2b], kb[4b]).
// lane's K-slice: k = q*64 + kb*4 + c  (q=0..7, c=0..3) -> coalesced f4 w2 loads.
// h transposed in LDS [k][m] as float4 over m, XOR-swizzled by (k>>2)&7 so
// per-read banks are broadcast(4 row_subs) x 2-way(kb vs kb+8) = conflict-free.
__global__ __launch_bounds__(256) void k_logits(const float* __restrict__ ws,
                                                const float* __restrict__ w2,
                                                const float* __restrict__ b2,
                                                float* __restrict__ out) {
  __shared__ float4 hT4[4096];   // 64 KB
  int tid = threadIdx.x;
  const float4* hg = (const float4*)(ws + OFF_H);
  for (int i = tid; i < 4096; i += 256) {
    int m = i >> 7, kf4 = i & 127;
    float4 hv = hg[i];
    int m4 = m >> 2, me = m & 3;
#pragma unroll
    for (int c = 0; c < 4; ++c) {
      int k = kf4 * 4 + c;
      int pf4 = k * 8 + (m4 ^ ((k >> 2) & 7));
      ((float*)hT4)[pf4 * 4 + me] = (&hv.x)[c];
    }
  }
  __syncthreads();
  int wv = tid >> 6, lane = tid & 63;
  int row_sub = lane >> 4, kb = lane & 15;
  int swz = kb & 7;
  int n_base = blockIdx.x * 64 + wv * 16;
  for (int j = 0; j < 4; ++j) {
    int row = n_base + j * 4 + row_sub;
    const float* wrow = w2 + (size_t)row * 512;
    float4 wseg[8];
#pragma unroll
    for (int q = 0; q < 8; ++q)
      wseg[q] = *(const float4*)(wrow + q * 64 + kb * 4);
    float accv[32];
#pragma unroll
    for (int m = 0; m < 32; ++m) accv[m] = 0.f;
#pragma unroll
    for (int q = 0; q < 8; ++q) {
#pragma unroll
      for (int c = 0; c < 4; ++c) {
        float wval = (&wseg[q].x)[c];
        int k = q * 64 + kb * 4 + c;
        const float4* hrow = hT4 + k * 8;
#pragma unroll
        for (int m4 = 0; m4 < 8; ++m4) {
          float4 hv = hrow[m4 ^ swz];
          accv[m4 * 4 + 0] = fmaf(hv.x, wval, accv[m4 * 4 + 0]);
          accv[m4 * 4 + 1] = fmaf(hv.y, wval, accv[m4 * 4 + 1]);
          accv[m4 * 4 + 2] = fmaf(hv.z, wval, accv[m4 * 4 + 2]);
          accv[m4 * 4 + 3] = fmaf(hv.w, wval, accv[m4 * 4 + 3]);
        }
      }
    }
    // reduce-scatter across kb bits: slot meaning tracks lane bits (positional,
    // all register indices compile-time).
    float r16[16];
#pragma unroll
    for (int i = 0; i < 16; ++i) {
      float a = accv[2 * i], bb = accv[2 * i + 1];
      float mine = (kb & 1) ? bb : a;
      float send = (kb & 1) ? a : bb;
      r16[i] = mine + __shfl_xor(send, 1, 64);
    }
    float r8[8];
#pragma unroll
    for (int i = 0; i < 8; ++i) {
      float a = r16[2 * i], bb = r16[2 * i + 1];
      float mine = (kb & 2) ? bb : a;
      float send = (kb & 2) ? a : bb;
      r8[i] = mine + __shfl_xor(send, 2, 64);
    }
    float r4[4];
#pragma unroll
    for (int i = 0; i < 4; ++i) {
      float a = r8[2 * i], bb = r8[2 * i + 1];
      float mine = (kb & 4) ? bb : a;
      float send = (kb & 4) ? a : bb;
      r4[i] = mine + __shfl_xor(send, 4, 64);
    }
    float r2[2];
#pragma unroll
    for (int i = 0; i < 2; ++i) {
      float a = r4[2 * i], bb = r4[2 * i + 1];
      float mine = (kb & 8) ? bb : a;
      float send = (kb & 8) ? a : bb;
      r2[i] = mine + __shfl_xor(send, 8, 64);
    }
    // lane holds m = kb and m = kb+16 for this row
    float bv = b2[row];
    out[(size_t)kb * 32000 + row]        = r2[0] + bv;
    out[(size_t)(kb + 16) * 32000 + row] = r2[1] + bv;
  }
}

}  // namespace

extern "C" void kernel_launch(void* const* d_in, const int* in_sizes, int n_in,
                              void* d_out, int out_size, void* d_ws, size_t ws_size,
                              hipStream_t stream) {
  (void)in_sizes; (void)n_in; (void)out_size; (void)ws_size;
  const int*   x    = (const int*)d_in[0];
  const float* emb  = (const float*)d_in[1];
  const float* wang = (const float*)d_in[2];
  const float* bang = (const float*)d_in[3];
  const float* coef = (const float*)d_in[4];
  const float* lre  = (const float*)d_in[5];
  const float* lim  = (const float*)d_in[6];
  const float* qff  = (const float*)d_in[7];
  const float* w1   = (const float*)d_in[8];
  const float* b1   = (const float*)d_in[9];
  const float* w2   = (const float*)d_in[10];
  const float* b2   = (const float*)d_in[11];
  float* out = (float*)d_out;
  float* ws  = (float*)d_ws;

  hipLaunchKernelGGL(k_prep,   dim3(1),    dim3(64),  0, stream, lre, lim, coef, qff, ws);
  hipLaunchKernelGGL(k_init,   dim3(128),  dim3(256), 0, stream, ws, coef);
  hipLaunchKernelGGL(k_angles, dim3(1024), dim3(128), 0, stream, x, emb, wang, bang, ws);
  for (int k = 1; k <= 3; ++k) {
    hipLaunchKernelGGL(k_evolve, dim3(256), dim3(256), 0, stream, ws);
    hipLaunchKernelGGL(k_reduce, dim3(128), dim3(256), 0, stream, ws, coef, k);
  }
  hipLaunchKernelGGL(k_final,  dim3(32),   dim3(64),  0, stream, ws);
  hipLaunchKernelGGL(k_mlp1,   dim3(64),   dim3(256), 0, stream, ws, w1, b1, out);
  hipLaunchKernelGGL(k_logits, dim3(500),  dim3(256), 0, stream, ws, w2, b2, out);
}

// Round 2
// 162.213 us; speedup vs baseline: 1.3857x; 1.3857x over previous
//
#include <hip/hip_runtime.h>
#include <math.h>

#define DEV __device__ __forceinline__

namespace {

struct C2 { float x, y; };

// ---------------- workspace layout (float offsets) ----------------
constexpr size_t OFF_CS   = 0;        // 1024 tokens * 80 gates * 2 (cos,sin)  = 163840
constexpr size_t OFF_QFF  = 163840;   // 40 gates * 2                           = 80
constexpr size_t OFF_LCU  = 163920;   // 32 * float2                            = 64
constexpr size_t OFF_DEN  = 163984;   // 1
constexpr size_t OFF_NRM  = 163988;   // 32
constexpr size_t OFF_MONO = 164096;   // 32*1024*float2                         = 65536
constexpr size_t OFF_ACC  = 229632;   // 65536
constexpr size_t OFF_ST   = 295168;   // 1024*1024*float2                       = 2097152
constexpr size_t OFF_EV   = 2392320;  // 32*30                                  = 960
constexpr size_t OFF_H    = 2393280;  // 32*512                                 = 16384

// ---------------- gate primitives ----------------
// amplitude index i = (reg<<6) | lane ; wire w lives at bit position P = 9 - w.

template<int P>
DEV void ry_gate(C2 v[16], int lane, float c, float s) {
  if constexpr (P >= 6) {
    constexpr int rm = 1 << (P - 6);
#pragma unroll
    for (int r = 0; r < 16; ++r) {
      if ((r & rm) == 0) {
        C2 a = v[r], b = v[r | rm];
        v[r].x      = fmaf(c, a.x, -s * b.x);
        v[r].y      = fmaf(c, a.y, -s * b.y);
        v[r | rm].x = fmaf(s, a.x,  c * b.x);
        v[r | rm].y = fmaf(s, a.y,  c * b.y);
      }
    }
  } else {
    constexpr int lm = 1 << P;
    float sg = (lane & lm) ? s : -s;
#pragma unroll
    for (int r = 0; r < 16; ++r) {
      float px = __shfl_xor(v[r].x, lm, 64);
      float py = __shfl_xor(v[r].y, lm, 64);
      v[r].x = fmaf(c, v[r].x, sg * px);
      v[r].y = fmaf(c, v[r].y, sg * py);
    }
  }
}

template<int PC, int PT>
DEV void crx_gate(C2 v[16], int lane, float c, float s) {
  if constexpr (PT >= 6) {
    constexpr int tm = 1 << (PT - 6);
#pragma unroll
    for (int r = 0; r < 16; ++r) {
      if ((r & tm) == 0) {
        if constexpr (PC >= 6) {
          constexpr int cm = 1 << (PC - 6);
          if ((r & cm) != 0) {
            C2 a = v[r], b = v[r | tm];
            v[r].x      = fmaf(c, a.x,  s * b.y);
            v[r].y      = fmaf(c, a.y, -s * b.x);
            v[r | tm].x = fmaf(c, b.x,  s * a.y);
            v[r | tm].y = fmaf(c, b.y, -s * a.x);
          }
        } else {
          constexpr int cl = 1 << PC;
          bool ct = (lane & cl) != 0;
          C2 a = v[r], b = v[r | tm];
          float nax = fmaf(c, a.x,  s * b.y);
          float nay = fmaf(c, a.y, -s * b.x);
          float nbx = fmaf(c, b.x,  s * a.y);
          float nby = fmaf(c, b.y, -s * a.x);
          v[r].x      = ct ? nax : a.x;
          v[r].y      = ct ? nay : a.y;
          v[r | tm].x = ct ? nbx : b.x;
          v[r | tm].y = ct ? nby : b.y;
        }
      }
    }
  } else {
    constexpr int tm = 1 << PT;
#pragma unroll
    for (int r = 0; r < 16; ++r) {
      if constexpr (PC >= 6) {
        constexpr int cm = 1 << (PC - 6);
        if ((r & cm) == 0) continue;
      }
      float px = __shfl_xor(v[r].x, tm, 64);
      float py = __shfl_xor(v[r].y, tm, 64);
      float nx = fmaf(c, v[r].x,  s * py);
      float ny = fmaf(c, v[r].y, -s * px);
      if constexpr (PC >= 6) {
        v[r].x = nx; v[r].y = ny;
      } else {
        constexpr int cl = 1 << PC;
        bool ct = (lane & cl) != 0;
        v[r].x = ct ? nx : v[r].x;
        v[r].y = ct ? ny : v[r].y;
      }
    }
  }
}

#define RYG(w, g)       ry_gate<9-(w)>(v, lane, cs[2*(g)], cs[2*(g)+1])
#define CRXG(cw, tw, g) crx_gate<9-(cw), 9-(tw)>(v, lane, cs[2*(g)], cs[2*(g)+1])

DEV void apply_layer(C2 v[16], int lane, const float* __restrict__ cs) {
  RYG(0,0); RYG(1,1); RYG(2,2); RYG(3,3); RYG(4,4);
  RYG(5,5); RYG(6,6); RYG(7,7); RYG(8,8); RYG(9,9);
  CRXG(9,0,10); CRXG(8,9,11); CRXG(7,8,12); CRXG(6,7,13); CRXG(5,6,14);
  CRXG(4,5,15); CRXG(3,4,16); CRXG(2,3,17); CRXG(1,2,18); CRXG(0,1,19);
  RYG(0,20); RYG(1,21); RYG(2,22); RYG(3,23); RYG(4,24);
  RYG(5,25); RYG(6,26); RYG(7,27); RYG(8,28); RYG(9,29);
  CRXG(9,8,30); CRXG(0,9,31); CRXG(1,0,32); CRXG(2,1,33); CRXG(3,2,34);
  CRXG(4,3,35); CRXG(5,4,36); CRXG(6,5,37); CRXG(7,6,38); CRXG(8,7,39);
}

template<int P>
DEV void measure_wire(const C2 v[16], int lane, float* ev, int w) {
  float x = 0.f, y = 0.f, z = 0.f;
  if constexpr (P >= 6) {
    constexpr int rm = 1 << (P - 6);
#pragma unroll
    for (int r = 0; r < 16; ++r) {
      if ((r & rm) == 0) {
        C2 a = v[r], b = v[r | rm];
        x += a.x*b.x + a.y*b.y;
        y += a.x*b.y - a.y*b.x;
        z += (a.x*a.x + a.y*a.y) - (b.x*b.x + b.y*b.y);
      }
    }
  } else {
    constexpr int lm = 1 << P;
#pragma unroll
    for (int r = 0; r < 16; ++r) {
      float px = __shfl_xor(v[r].x, lm, 64);
      float py = __shfl_xor(v[r].y, lm, 64);
      if ((lane & lm) == 0) {
        C2 a = v[r];
        x += a.x*px + a.y*py;
        y += a.x*py - a.y*px;
        z += (a.x*a.x + a.y*a.y) - (px*px + py*py);
      }
    }
  }
  for (int s = 1; s < 64; s <<= 1) {
    x += __shfl_xor(x, s, 64);
    y += __shfl_xor(y, s, 64);
    z += __shfl_xor(z, s, 64);
  }
  if (lane == 0) {
    ev[w]      = 2.f * x;
    ev[10 + w] = 2.f * y;
    ev[20 + w] = z;
  }
}

DEV void measure_all(const C2 v[16], int lane, float* ev) {
  measure_wire<9>(v, lane, ev, 0);
  measure_wire<8>(v, lane, ev, 1);
  measure_wire<7>(v, lane, ev, 2);
  measure_wire<6>(v, lane, ev, 3);
  measure_wire<5>(v, lane, ev, 4);
  measure_wire<4>(v, lane, ev, 5);
  measure_wire<3>(v, lane, ev, 6);
  measure_wire<2>(v, lane, ev, 7);
  measure_wire<1>(v, lane, ev, 8);
  measure_wire<0>(v, lane, ev, 9);
}

// ---------------- kernels ----------------

// K_init (+fused prep): mono = e0, acc = coeffs[0]*e0; block 0 wave 0 also does
// lcu normalize / |coeffs| / qff cos-sin. 128x256.
__global__ void k_init(float* __restrict__ ws, const float* __restrict__ coef,
                       const float* __restrict__ lr, const float* __restrict__ li,
                       const float* __restrict__ qff) {
  if (blockIdx.x == 0 && threadIdx.x < 64) {
    int lane = threadIdx.x;
    float re = 0.f, im = 0.f;
    if (lane < 32) { re = lr[lane]; im = li[lane]; }
    float tot = sqrtf(re * re + im * im);
    for (int s = 1; s < 64; s <<= 1) tot += __shfl_xor(tot, s, 64);
    float L = fmaxf(tot, 1e-12f);
    if (lane < 32) {
      ws[OFF_LCU + 2 * lane]     = re / L;
      ws[OFF_LCU + 2 * lane + 1] = im / L;
    }
    float dv = (lane < 4) ? fabsf(coef[lane]) : 0.f;
    for (int s = 1; s < 64; s <<= 1) dv += __shfl_xor(dv, s, 64);
    if (lane == 0) ws[OFF_DEN] = dv;
    if (lane < 40) {
      float th = 0.5f * qff[lane];
      ws[OFF_QFF + 2 * lane]     = cosf(th);
      ws[OFF_QFF + 2 * lane + 1] = sinf(th);
    }
  }
  int idx = blockIdx.x * 256 + threadIdx.x;   // 0..32767 over (b,i)
  float c0 = coef[0];
  bool z = (idx & 1023) == 0;
  float2* mono = (float2*)(ws + OFF_MONO);
  float2* acc  = (float2*)(ws + OFF_ACC);
  mono[idx] = make_float2(z ? 1.f : 0.f, 0.f);
  acc[idx]  = make_float2(z ? c0 : 0.f, 0.f);
}

// K1: angles = emb[x] @ w_ang.T + b_ang -> (cos,sin)(theta/2). one token/block.
__global__ __launch_bounds__(128) void k_angles(const int* __restrict__ x,
                                                const float* __restrict__ emb,
                                                const float* __restrict__ w_ang,
                                                const float* __restrict__ b_ang,
                                                float* __restrict__ ws) {
  __shared__ float4 e4[128];
  int tok = blockIdx.x;
  int tid = threadIdx.x;
  int row = x[tok];
  e4[tid] = ((const float4*)(emb + (size_t)row * 512))[tid];
  __syncthreads();
  if (tid < 80) {
    const float4* wr = (const float4*)(w_ang + (size_t)tid * 512);
    float acc = b_ang[tid];
#pragma unroll 4
    for (int j = 0; j < 128; ++j) {
      float4 w = wr[j];
      float4 e = e4[j];
      acc = fmaf(w.x, e.x, acc);
      acc = fmaf(w.y, e.y, acc);
      acc = fmaf(w.z, e.z, acc);
      acc = fmaf(w.w, e.w, acc);
    }
    float th = 0.5f * acc;
    ws[OFF_CS + (size_t)tok * 160 + 2 * tid]     = cosf(th);
    ws[OFF_CS + (size_t)tok * 160 + 2 * tid + 1] = sinf(th);
  }
}

// K2: evolve. one wave per (b,t) state; full state in 32 VGPR/lane.
__global__ __launch_bounds__(256) void k_evolve(float* __restrict__ ws) {
  __shared__ float cs_lds[640];
  int tid = threadIdx.x;
  const float* csg = ws + OFF_CS + (size_t)blockIdx.x * 640;
  for (int i = tid; i < 640; i += 256) cs_lds[i] = csg[i];
  __syncthreads();
  int wid = tid >> 6, lane = tid & 63;
  int state = blockIdx.x * 4 + wid;
  int b = state >> 5, t = state & 31;
  const float2* mono = (const float2*)(ws + OFF_MONO) + (size_t)b * 1024;
  C2 v[16];
#pragma unroll
  for (int r = 0; r < 16; ++r) {
    float2 m = mono[(r << 6) | lane];
    v[r].x = m.x; v[r].y = m.y;
  }
  const float* csw = &cs_lds[wid * 160];
#pragma unroll 1
  for (int l = 0; l < 2; ++l)
    apply_layer(v, lane, csw + l * 80);
  float2 w = ((const float2*)(ws + OFF_LCU))[t];
  float2* st = (float2*)(ws + OFF_ST) + (size_t)state * 1024;
#pragma unroll
  for (int r = 0; r < 16; ++r) {
    st[(r << 6) | lane] = make_float2(w.x * v[r].x - w.y * v[r].y,
                                      w.x * v[r].y + w.y * v[r].x);
  }
}

// K3: mono[b] = sum_t st[b,t]; acc += coeffs[k]*mono. 128x256.
__global__ void k_reduce(float* __restrict__ ws, const float* __restrict__ coef, int k) {
  int idx = blockIdx.x * 256 + threadIdx.x;
  int b = idx >> 10, i = idx & 1023;
  const float2* st = (const float2*)(ws + OFF_ST) + (size_t)b * 32768 + i;
  float sx = 0.f, sy = 0.f;
#pragma unroll
  for (int t = 0; t < 32; ++t) {
    float2 vv = st[t * 1024];
    sx += vv.x; sy += vv.y;
  }
  float2* mono = (float2*)(ws + OFF_MONO);
  float2* acc  = (float2*)(ws + OFF_ACC);
  mono[idx] = make_float2(sx, sy);
  float ck = coef[k];
  float2 a = acc[idx];
  a.x = fmaf(ck, sx, a.x);
  a.y = fmaf(ck, sy, a.y);
  acc[idx] = a;
}

// K5: qsvt_state = acc/den; norm; normalize; 1-layer qff; measure XYZ. 1 wave/b.
__global__ __launch_bounds__(64) void k_final(float* __restrict__ ws) {
  int lane = threadIdx.x;
  int b = blockIdx.x;
  const float2* acc = (const float2*)(ws + OFF_ACC) + (size_t)b * 1024;
  float invd = 1.f / ws[OFF_DEN];
  C2 v[16];
  float ssum = 0.f;
#pragma unroll
  for (int r = 0; r < 16; ++r) {
    float2 m = acc[(r << 6) | lane];
    v[r].x = m.x * invd; v[r].y = m.y * invd;
    ssum += v[r].x * v[r].x + v[r].y * v[r].y;
  }
  for (int s = 1; s < 64; s <<= 1) ssum += __shfl_xor(ssum, s, 64);
  float nrm = sqrtf(ssum);
  if (lane == 0) ws[OFF_NRM + b] = nrm;
  float sc = 1.f / fmaxf(nrm, 1e-12f);
#pragma unroll
  for (int r = 0; r < 16; ++r) { v[r].x *= sc; v[r].y *= sc; }
  apply_layer(v, lane, ws + OFF_QFF);
  measure_all(v, lane, ws + OFF_EV + b * 30);
}

// K6: h = relu(ev @ w1.T + b1); also mean(norm). 64x256.
__global__ void k_mlp1(float* __restrict__ ws, const float* __restrict__ w1,
                       const float* __restrict__ b1, float* __restrict__ out) {
  int idx = blockIdx.x * 256 + threadIdx.x;
  int b = idx >> 9, j = idx & 511;
  const float* ev = ws + OFF_EV + b * 30;
  const float* wr = w1 + (size_t)j * 30;
  float a = b1[j];
#pragma unroll
  for (int q = 0; q < 30; ++q) a = fmaf(ev[q], wr[q], a);
  ws[OFF_H + idx] = fmaxf(a, 0.f);
  if (idx == 0) {
    float s = 0.f;
    for (int i = 0; i < 32; ++i) s += ws[OFF_NRM + i];
    out[32000u * 32u] = s * (1.f / 32.f);
  }
}

// K7 v2: logits = h @ w2.T + b2.  M=32, N=32000, K=512.
// 250 blocks x 256 thr. Block owns 128 vocab rows. Wave wv owns K-quarter.
// Lane (mg = l&3, nl = l>>2): 8 m's (mg*8+mi) x 8 n's (nbase+nl*8+j), 64 accs.
// h tile in LDS [m][kf4] f4, XOR-swizzled by (m>>3) so the 4 concurrent
// addresses (differing only in mg) land on distinct bank quads.
// ds:FMA ratio = 1:32 -> VALU-bound (~7us floor), not LDS-bound.
// K-quarters combined via fixed-order LDS tree (deterministic).
__global__ __launch_bounds__(256) void k_logits(const float* __restrict__ ws,
                                                const float* __restrict__ w2,
                                                const float* __restrict__ b2,
                                                float* __restrict__ out) {
  __shared__ float4 hT[4096];   // 64 KB: h tile, then reused as combine buffer
  int tid = threadIdx.x;
  const float4* hg = (const float4*)(ws + OFF_H);   // [32][128] f4
#pragma unroll
  for (int p = 0; p < 16; ++p) {
    int idx = tid + p * 256;
    int m = idx >> 7, kf4 = idx & 127;
    hT[m * 128 + (kf4 ^ (m >> 3))] = hg[idx];
  }
  __syncthreads();

  int wv = tid >> 6, lane = tid & 63;
  int mg = lane & 3, nl = lane >> 2;
  int nbase = blockIdx.x * 128;
  float acc[8][8];   // [j][mi]
#pragma unroll
  for (int j = 0; j < 8; ++j)
#pragma unroll
    for (int mi = 0; mi < 8; ++mi) acc[j][mi] = 0.f;

  const float* wbase = w2 + (size_t)(nbase + nl * 8) * 512 + wv * 128;
  int kqb = wv * 32;
  for (int kf4 = 0; kf4 < 32; ++kf4) {
    int kcol = kqb + kf4;
    float4 h4[8];
#pragma unroll
    for (int mi = 0; mi < 8; ++mi) {
      int m = mg * 8 + mi;
      h4[mi] = hT[m * 128 + (kcol ^ mg)];
    }
#pragma unroll
    for (int j = 0; j < 8; ++j) {
      float4 w4 = *(const float4*)(wbase + (size_t)j * 512 + kf4 * 4);
#pragma unroll
      for (int mi = 0; mi < 8; ++mi) {
        acc[j][mi] = fmaf(w4.x, h4[mi].x, acc[j][mi]);
        acc[j][mi] = fmaf(w4.y, h4[mi].y, acc[j][mi]);
        acc[j][mi] = fmaf(w4.z, h4[mi].z, acc[j][mi]);
        acc[j][mi] = fmaf(w4.w, h4[mi].w, acc[j][mi]);
      }
    }
  }

  // ---- combine K-quarters: waves 1..3 stage accs; wave 0 sums (fixed order) ----
  __syncthreads();
  if (wv != 0) {
    int r = wv - 1;
    float4* cb = hT + r * 1024 + lane * 16;
#pragma unroll
    for (int mi = 0; mi < 8; ++mi) {
#pragma unroll
      for (int jh = 0; jh < 2; ++jh) {
        int q = mi * 2 + jh;
        float4 vv = make_float4(acc[jh*4+0][mi], acc[jh*4+1][mi],
                                acc[jh*4+2][mi], acc[jh*4+3][mi]);
        cb[q ^ (lane & 15)] = vv;
      }
    }
  }
  __syncthreads();
  if (wv == 0) {
#pragma unroll
    for (int r = 0; r < 3; ++r) {
      const float4* cb = hT + r * 1024 + lane * 16;
#pragma unroll
      for (int mi = 0; mi < 8; ++mi) {
#pragma unroll
        for (int jh = 0; jh < 2; ++jh) {
          int q = mi * 2 + jh;
          float4 vv = cb[q ^ (lane & 15)];
          acc[jh*4+0][mi] += vv.x;
          acc[jh*4+1][mi] += vv.y;
          acc[jh*4+2][mi] += vv.z;
          acc[jh*4+3][mi] += vv.w;
        }
      }
    }
    float4 b2lo = *(const float4*)(b2 + nbase + nl * 8);
    float4 b2hi = *(const float4*)(b2 + nbase + nl * 8 + 4);
#pragma unroll
    for (int mi = 0; mi < 8; ++mi) {
      int m = mg * 8 + mi;
      float* orow = out + (size_t)m * 32000 + nbase + nl * 8;
      float4 lo = make_float4(acc[0][mi] + b2lo.x, acc[1][mi] + b2lo.y,
                              acc[2][mi] + b2lo.z, acc[3][mi] + b2lo.w);
      float4 hi = make_float4(acc[4][mi] + b2hi.x, acc[5][mi] + b2hi.y,
                              acc[6][mi] + b2hi.z, acc[7][mi] + b2hi.w);
      *(float4*)(orow)     = lo;
      *(float4*)(orow + 4) = hi;
    }
  }
}

}  // namespace

extern "C" void kernel_launch(void* const* d_in, const int* in_sizes, int n_in,
                              void* d_out, int out_size, void* d_ws, size_t ws_size,
                              hipStream_t stream) {
  (void)in_sizes; (void)n_in; (void)out_size; (void)ws_size;
  const int*   x    = (const int*)d_in[0];
  const float* emb  = (const float*)d_in[1];
  const float* wang = (const float*)d_in[2];
  const float* bang = (const float*)d_in[3];
  const float* coef = (const float*)d_in[4];
  const float* lre  = (const float*)d_in[5];
  const float* lim  = (const float*)d_in[6];
  const float* qff  = (const float*)d_in[7];
  const float* w1   = (const float*)d_in[8];
  const float* b1   = (const float*)d_in[9];
  const float* w2   = (const float*)d_in[10];
  const float* b2   = (const float*)d_in[11];
  float* out = (float*)d_out;
  float* ws  = (float*)d_ws;

  hipLaunchKernelGGL(k_init,   dim3(128),  dim3(256), 0, stream, ws, coef, lre, lim, qff);
  hipLaunchKernelGGL(k_angles, dim3(1024), dim3(128), 0, stream, x, emb, wang, bang, ws);
  for (int k = 1; k <= 3; ++k) {
    hipLaunchKernelGGL(k_evolve, dim3(256), dim3(256), 0, stream, ws);
    hipLaunchKernelGGL(k_reduce, dim3(128), dim3(256), 0, stream, ws, coef, k);
  }
  hipLaunchKernelGGL(k_final,  dim3(32),   dim3(64),  0, stream, ws);
  hipLaunchKernelGGL(k_mlp1,   dim3(64),   dim3(256), 0, stream, ws, w1, b1, out);
  hipLaunchKernelGGL(k_logits, dim3(250),  dim3(256), 0, stream, ws, w2, b2, out);
}